// Round 7
// baseline (200.990 us; speedup 1.0000x reference)
//
#include <hip/hip_runtime.h>
#include <math.h>

#define L 250000
#define FEAT 100
#define HID 50
#define HS 165
#define CQ 50257
#define EXTV 1000
#define NOUT (CQ + EXTV)   // 51257

#define NBLK23 1024
#define NW23 (NBLK23 * 4)   // 4096 waves
#define NBLK5 512
#define NW5 (NBLK5 * 4)     // 2048 waves

// workspace float offsets
#define WS_Q     0      // 100
#define WS_P1    100
#define WS_P2    101
#define WS_SCALE 102    // p2/denom
#define WS_DENOM 103
#define WS_CT    104    // 100
#define WS_ET    204    // 200 (16B aligned)
#define WS_H     404    // 50
#define WS_LSE   454
#define WS_CNT1  456    // int counter (k23 lastblock)
#define WS_CNT2  457    // int counter (k5 lastblock)
#define WS_ADD   512    // 51257 raw scatter accumulator
#define WS_OUT   51776  // 51257 pre-logsoftmax vocab
#define WS_MS    103040 // 512*2 (m,s) pairs
#define WS_PT    104448 // 1024*104 block partials [blk][col], col 100 = denom

__device__ __forceinline__ float sigm(float x) { return 1.f / (1.f + expf(-x)); }

// ---------------- K1: LSTM step + q + p1/p2 ; zero add_buf + counters --------
__global__ void k1_lstm(const float* __restrict__ y, const float* __restrict__ h0,
                        const float* __restrict__ c0,
                        const float* __restrict__ W_ih, const float* __restrict__ W_hh,
                        const float* __restrict__ b_ih, const float* __restrict__ b_hh,
                        const float* __restrict__ w_h_W, const float* __restrict__ w_h_b,
                        const float* __restrict__ l3_W, const float* __restrict__ l3_b,
                        const float* __restrict__ l4_W, const float* __restrict__ l4_b,
                        float* __restrict__ ws, float* __restrict__ out) {
    int t = threadIdx.x;
    if (blockIdx.x != 0) {
        // zero add_buf (grid-stride over blocks 1..63)
        float* add = ws + WS_ADD;
        for (int i = (blockIdx.x - 1) * 256 + t; i < NOUT; i += 63 * 256) add[i] = 0.f;
        return;
    }
    __shared__ float s_y[HS], s_h[HID], s_c[HID], s_g[4 * HID], s_hn[HID];
    if (t < HS) s_y[t] = y[t];
    if (t < HID) { s_h[t] = h0[t]; s_c[t] = c0[t]; }
    if (t == 203) ((int*)ws)[WS_CNT1] = 0;
    if (t == 204) ((int*)ws)[WS_CNT2] = 0;
    __syncthreads();
    if (t < 4 * HID) {
        float acc = b_ih[t] + b_hh[t];
        const float* wi = W_ih + t * HS;
        for (int k = 0; k < HS; ++k) acc += wi[k] * s_y[k];
        const float* wh = W_hh + t * HID;
        for (int k = 0; k < HID; ++k) acc += wh[k] * s_h[k];
        s_g[t] = acc;
    }
    __syncthreads();
    if (t < HID) {
        float ig = sigm(s_g[t]);
        float fg = sigm(s_g[HID + t]);
        float gg = tanhf(s_g[2 * HID + t]);
        float og = sigm(s_g[3 * HID + t]);
        float cn = fg * s_c[t] + ig * gg;
        float hn = og * tanhf(cn);
        s_hn[t] = hn;
        ws[WS_H + t] = hn;
        out[NOUT + t] = hn;          // h_new output
        out[NOUT + HID + t] = cn;    // c_new output
    }
    __syncthreads();
    if (t < FEAT) {
        float acc = w_h_b[t];
        const float* w = w_h_W + t * HID;
        for (int k = 0; k < HID; ++k) acc += w[k] * s_hn[k];
        ws[WS_Q + t] = acc;
    }
    if (t == 200) {
        float acc = l3_b[0];
        for (int k = 0; k < HID; ++k) acc += l3_W[k] * s_hn[k];
        ws[WS_P1] = sigm(acc);
    }
    if (t == 201) {
        float acc = l4_b[0];
        for (int k = 0; k < HID; ++k) acc += l4_W[k] * s_hn[k];
        ws[WS_P2] = sigm(acc);
    }
}

// ------- K23: wave-per-row pass over H: scatter e, block partials; ------------
// last block reduces partials -> ct, denom, then computes e_t (= old k3r+k4).
__global__ void __launch_bounds__(256)
k23_fused(const float* __restrict__ H, const int* __restrict__ cont,
          float* __restrict__ ws,
          const float* __restrict__ l1_W, const float* __restrict__ l1_b) {
    __shared__ float s_ct[4][FEAT];
    __shared__ float s_d[4];
    __shared__ float s_t[152];
    __shared__ float s_den;
    __shared__ int s_last;
    int t = threadIdx.x;
    int w = t >> 6, lane = t & 63;
    long wid = (long)blockIdx.x * 4 + w;
    float q0 = ws[WS_Q + lane];
    float q1 = (lane < 36) ? ws[WS_Q + 64 + lane] : 0.f;
    long r0 = (wid * L) / NW23;
    long r1 = ((wid + 1) * L) / NW23;
    float c0a = 0.f, c1a = 0.f, dacc = 0.f;
    float* add = ws + WS_ADD;

    long r = r0;
    float h0a = 0.f, h1a = 0.f, h0b = 0.f, h1b = 0.f;
    if (r < r1) {
        const float* p = H + r * FEAT;
        h0a = p[lane]; h1a = (lane < 36) ? p[64 + lane] : 0.f;
    }
    if (r + 1 < r1) {
        const float* p = H + (r + 1) * FEAT;
        h0b = p[lane]; h1b = (lane < 36) ? p[64 + lane] : 0.f;
    }
    for (; r + 2 <= r1; r += 2) {
        float h0c = 0.f, h1c = 0.f, h0d = 0.f, h1d = 0.f;
        if (r + 2 < r1) {
            const float* p = H + (r + 2) * FEAT;
            h0c = p[lane]; h1c = (lane < 36) ? p[64 + lane] : 0.f;
        }
        if (r + 3 < r1) {
            const float* p = H + (r + 3) * FEAT;
            h0d = p[lane]; h1d = (lane < 36) ? p[64 + lane] : 0.f;
        }
        float pa = h0a * q0 + h1a * q1;
        float pb = h0b * q0 + h1b * q1;
#pragma unroll
        for (int o = 1; o < 64; o <<= 1) {
            pa += __shfl_xor(pa, o);
            pb += __shfl_xor(pb, o);
        }
        float ea = expf(pa), eb = expf(pb);
        if (lane == 0) {
            int ca = cont[r], cb = cont[r + 1];
            atomicAdd(&add[ca], ea);
            atomicAdd(&add[cb], eb);
            dacc += ea + eb;
        }
        c0a += ea * h0a + eb * h0b;
        c1a += ea * h1a + eb * h1b;
        h0a = h0c; h1a = h1c; h0b = h0d; h1b = h1d;
    }
    if (r < r1) {   // tail row (already in h0a/h1a)
        float pa = h0a * q0 + h1a * q1;
#pragma unroll
        for (int o = 1; o < 64; o <<= 1) pa += __shfl_xor(pa, o);
        float ea = expf(pa);
        if (lane == 0) {
            atomicAdd(&add[cont[r]], ea);
            dacc += ea;
        }
        c0a += ea * h0a;
        c1a += ea * h1a;
    }
    s_ct[w][lane] = c0a;
    if (lane < 36) s_ct[w][64 + lane] = c1a;
    if (lane == 0) s_d[w] = dacc;
    __syncthreads();
    float* pt = ws + WS_PT;
    if (t < FEAT)
        pt[blockIdx.x * 104 + t] = s_ct[0][t] + s_ct[1][t] + s_ct[2][t] + s_ct[3][t];
    if (t == FEAT)
        pt[blockIdx.x * 104 + FEAT] = s_d[0] + s_d[1] + s_d[2] + s_d[3];
    __threadfence();
    __syncthreads();
    if (t == 0) {
        int old = atomicAdd((int*)ws + WS_CNT1, 1);
        s_last = (old == NBLK23 - 1) ? 1 : 0;
    }
    __syncthreads();
    if (!s_last) return;

    // ---- last block: reduce partials -> ct, denom ----
    __threadfence();
    if (t < FEAT + 1) {
        float s = 0.f;
        for (int b = 0; b < NBLK23; ++b) s += pt[b * 104 + t];
        if (t < FEAT) ws[WS_CT + t] = s;
        else ws[WS_DENOM] = s;
    }
    __syncthreads();
    // ---- k4 portion: temp = [h ; ct/denom], e_t = sigmoid(l1), scale ----
    if (t == 0) {
        float d = ws[WS_DENOM];
        s_den = d;
        ws[WS_SCALE] = ws[WS_P2] / d;
    }
    __syncthreads();
    if (t < HID) s_t[t] = ws[WS_H + t];
    if (t < FEAT) s_t[HID + t] = ws[WS_CT + t] / s_den;
    __syncthreads();
    if (t < 200) {
        float acc = l1_b[t];
        const float* wv = l1_W + t * 150;
        for (int k = 0; k < 150; ++k) acc += wv[k] * s_t[k];
        ws[WS_ET + t] = sigm(acc);
    }
}

// ------- K5: out[r] = p1*(l2_W[r].e_t + b) + scale*add[r]; online (m,s); -----
// last block merges block partials -> lse.
__global__ void __launch_bounds__(256)
k5_vocab(const float* __restrict__ l2_W, const float* __restrict__ l2_b,
         float* __restrict__ ws, float* __restrict__ outv) {
    __shared__ float4 s_e[50];
    __shared__ float s_ms[8];
    __shared__ int s_last;
    int t = threadIdx.x, w = t >> 6, lane = t & 63;
    if (t < 50) s_e[t] = ((const float4*)(ws + WS_ET))[t];
    __syncthreads();
    float p1 = ws[WS_P1], scale = ws[WS_SCALE];
    const float* add = ws + WS_ADD;
    float m = -1e30f, s = 0.f;
    for (int r = blockIdx.x * 4 + w; r < NOUT; r += NW5) {
        float acc = 0.f;
        if (r < CQ && lane < 50) {
            float4 a = ((const float4*)l2_W)[(size_t)r * 50 + lane];
            float4 b = s_e[lane];
            acc = a.x * b.x + a.y * b.y + a.z * b.z + a.w * b.w;
        }
#pragma unroll
        for (int o = 32; o > 0; o >>= 1) acc += __shfl_down(acc, o);
        if (lane == 0) {
            float val = (r < CQ) ? p1 * (acc + l2_b[r]) + scale * add[r]
                                 : scale * add[r];
            outv[r] = val;
            float mn = fmaxf(m, val);
            s = s * expf(m - mn) + expf(val - mn);
            m = mn;
        }
    }
    if (lane == 0) { s_ms[w * 2] = m; s_ms[w * 2 + 1] = s; }
    __syncthreads();
    float* msbuf = ws + WS_MS;
    if (t == 0) {
        float mg = s_ms[0], sg = s_ms[1];
        for (int k = 1; k < 4; ++k) {
            float mb = s_ms[2 * k], sb = s_ms[2 * k + 1];
            float mn = fmaxf(mg, mb);
            sg = sg * expf(mg - mn) + sb * expf(mb - mn);
            mg = mn;
        }
        msbuf[blockIdx.x * 2] = mg;
        msbuf[blockIdx.x * 2 + 1] = sg;
    }
    __threadfence();
    __syncthreads();
    if (t == 0) {
        int old = atomicAdd((int*)ws + WS_CNT2, 1);
        s_last = (old == NBLK5 - 1) ? 1 : 0;
    }
    __syncthreads();
    if (!s_last) return;

    __threadfence();
    float mg = -1e30f, sg = 0.f;
    for (int k = t; k < NBLK5; k += 256) {
        float mb = msbuf[2 * k], sb = msbuf[2 * k + 1];
        float mn = fmaxf(mg, mb);
        sg = sg * expf(mg - mn) + sb * expf(mb - mn);
        mg = mn;
    }
#pragma unroll
    for (int o = 1; o < 64; o <<= 1) {
        float mb = __shfl_xor(mg, o), sb = __shfl_xor(sg, o);
        float mn = fmaxf(mg, mb);
        sg = sg * expf(mg - mn) + sb * expf(mb - mn);
        mg = mn;
    }
    if (lane == 0) { s_ms[w * 2] = mg; s_ms[w * 2 + 1] = sg; }
    __syncthreads();
    if (t == 0) {
        float M = s_ms[0], S = s_ms[1];
        for (int k = 1; k < 4; ++k) {
            float mb = s_ms[2 * k], sb = s_ms[2 * k + 1];
            float mn = fmaxf(M, mb);
            S = S * expf(M - mn) + sb * expf(mb - mn);
            M = mn;
        }
        ws[WS_LSE] = M + logf(S);
    }
}

// ---------------- K7c: final subtract ----------------
__global__ void k7c_final(const float* __restrict__ outv, const float* __restrict__ ws,
                          float* __restrict__ dout) {
    float lse = ws[WS_LSE];
    int j = blockIdx.x * blockDim.x + threadIdx.x;
    if (j < NOUT) dout[j] = outv[j] - lse;
}

extern "C" void kernel_launch(void* const* d_in, const int* in_sizes, int n_in,
                              void* d_out, int out_size, void* d_ws, size_t ws_size,
                              hipStream_t stream) {
    const float* H    = (const float*)d_in[0];
    const float* y    = (const float*)d_in[1];
    const float* h0   = (const float*)d_in[2];
    const float* c0   = (const float*)d_in[3];
    const int*   cont = (const int*)d_in[4];
    // d_in[5] = ext scalar (1000), hardcoded
    const float* W_ih = (const float*)d_in[6];
    const float* W_hh = (const float*)d_in[7];
    const float* b_ih = (const float*)d_in[8];
    const float* b_hh = (const float*)d_in[9];
    const float* w_h_W = (const float*)d_in[10];
    const float* w_h_b = (const float*)d_in[11];
    const float* l1_W = (const float*)d_in[12];
    const float* l1_b = (const float*)d_in[13];
    const float* l2_W = (const float*)d_in[14];
    const float* l2_b = (const float*)d_in[15];
    const float* l3_W = (const float*)d_in[16];
    const float* l3_b = (const float*)d_in[17];
    const float* l4_W = (const float*)d_in[18];
    const float* l4_b = (const float*)d_in[19];

    float* ws  = (float*)d_ws;
    float* out = (float*)d_out;

    k1_lstm<<<64, 256, 0, stream>>>(y, h0, c0, W_ih, W_hh, b_ih, b_hh,
                                    w_h_W, w_h_b, l3_W, l3_b, l4_W, l4_b, ws, out);

    k23_fused<<<NBLK23, 256, 0, stream>>>(H, cont, ws, l1_W, l1_b);

    k5_vocab<<<NBLK5, 256, 0, stream>>>(l2_W, l2_b, ws, ws + WS_OUT);

    k7c_final<<<(NOUT + 255) / 256, 256, 0, stream>>>(ws + WS_OUT, ws, out);
}

// Round 8
// 126.514 us; speedup vs baseline: 1.5887x; 1.5887x over previous
//
#include <hip/hip_runtime.h>
#include <math.h>

#define L 250000
#define FEAT 100
#define HID 50
#define HS 165
#define CQ 50257
#define EXTV 1000
#define NOUT (CQ + EXTV)   // 51257

#define NBLK23 1024
#define NW23 (NBLK23 * 4)   // 4096 waves, ~61 rows/wave
#define NBLK5 512
#define NW5 (NBLK5 * 4)     // 2048 waves
#define NCOL 101            // 100 ct cols + denom

// workspace float offsets
#define WS_Q     0      // 100
#define WS_P1    100
#define WS_P2    101
#define WS_SCALE 102    // p2/denom
#define WS_DENOM 103
#define WS_CT    104    // 100
#define WS_ET    204    // 200 (16B aligned)
#define WS_H     404    // 50
#define WS_LSE   454
#define WS_CNT1  456    // int counter (k3r4 lastblock)
#define WS_CNT2  457    // int counter (k5 lastblock)
#define WS_ADD   512    // 51257 raw scatter accumulator
#define WS_OUT   51776  // 51257 pre-logsoftmax vocab
#define WS_MS    103040 // 512*2 (m,s) pairs
#define WS_PT    104448 // 101*1024 block partials [col][blk]

__device__ __forceinline__ float sigm(float x) { return 1.f / (1.f + expf(-x)); }

// ---------------- K1: LSTM step + q + p1/p2 ; zero add_buf + counters --------
__global__ void k1_lstm(const float* __restrict__ y, const float* __restrict__ h0,
                        const float* __restrict__ c0,
                        const float* __restrict__ W_ih, const float* __restrict__ W_hh,
                        const float* __restrict__ b_ih, const float* __restrict__ b_hh,
                        const float* __restrict__ w_h_W, const float* __restrict__ w_h_b,
                        const float* __restrict__ l3_W, const float* __restrict__ l3_b,
                        const float* __restrict__ l4_W, const float* __restrict__ l4_b,
                        float* __restrict__ ws, float* __restrict__ out) {
    int t = threadIdx.x;
    if (blockIdx.x != 0) {
        float* add = ws + WS_ADD;
        for (int i = (blockIdx.x - 1) * 256 + t; i < NOUT; i += 63 * 256) add[i] = 0.f;
        return;
    }
    __shared__ float s_y[HS], s_h[HID], s_c[HID], s_g[4 * HID], s_hn[HID];
    if (t < HS) s_y[t] = y[t];
    if (t < HID) { s_h[t] = h0[t]; s_c[t] = c0[t]; }
    if (t == 203) ((int*)ws)[WS_CNT1] = 0;
    if (t == 204) ((int*)ws)[WS_CNT2] = 0;
    __syncthreads();
    if (t < 4 * HID) {
        float acc = b_ih[t] + b_hh[t];
        const float* wi = W_ih + t * HS;
        for (int k = 0; k < HS; ++k) acc += wi[k] * s_y[k];
        const float* wh = W_hh + t * HID;
        for (int k = 0; k < HID; ++k) acc += wh[k] * s_h[k];
        s_g[t] = acc;
    }
    __syncthreads();
    if (t < HID) {
        float ig = sigm(s_g[t]);
        float fg = sigm(s_g[HID + t]);
        float gg = tanhf(s_g[2 * HID + t]);
        float og = sigm(s_g[3 * HID + t]);
        float cn = fg * s_c[t] + ig * gg;
        float hn = og * tanhf(cn);
        s_hn[t] = hn;
        ws[WS_H + t] = hn;
        out[NOUT + t] = hn;          // h_new output
        out[NOUT + HID + t] = cn;    // c_new output
    }
    __syncthreads();
    if (t < FEAT) {
        float acc = w_h_b[t];
        const float* w = w_h_W + t * HID;
        for (int k = 0; k < HID; ++k) acc += w[k] * s_hn[k];
        ws[WS_Q + t] = acc;
    }
    if (t == 200) {
        float acc = l3_b[0];
        for (int k = 0; k < HID; ++k) acc += l3_W[k] * s_hn[k];
        ws[WS_P1] = sigm(acc);
    }
    if (t == 201) {
        float acc = l4_b[0];
        for (int k = 0; k < HID; ++k) acc += l4_W[k] * s_hn[k];
        ws[WS_P2] = sigm(acc);
    }
}

// ------- K23: wave-per-row pass over H: partials + wave-wide scatter ---------
// Lane l owns columns l and l+64. Per row: 2 coalesced loads, butterfly dot,
// e = exp(dot) (wave-uniform). Lane (r-r0) keeps its row's e in a register;
// at loop end ONE wave-wide atomic scatter (coalesced cont load) does the
// pointer-copy accumulation. No divergence in the loop, no per-row atomics.
__global__ void __launch_bounds__(256)
k23_fused(const float* __restrict__ H, const int* __restrict__ cont,
          float* __restrict__ ws, float* __restrict__ pt) {
    __shared__ float s_ct[4][FEAT];
    __shared__ float s_d[4];
    int t = threadIdx.x;
    int w = t >> 6, lane = t & 63;
    long wid = (long)blockIdx.x * 4 + w;
    float q0 = ws[WS_Q + lane];
    float q1 = (lane < 36) ? ws[WS_Q + 64 + lane] : 0.f;
    long r0 = (wid * L) / NW23;
    long r1 = ((wid + 1) * L) / NW23;
    float c0a = 0.f, c1a = 0.f, dacc = 0.f;
    float my_e = 0.f;

    long r = r0;
    float h0a = 0.f, h1a = 0.f, h0b = 0.f, h1b = 0.f;
    if (r < r1) {
        const float* p = H + r * FEAT;
        h0a = p[lane]; h1a = (lane < 36) ? p[64 + lane] : 0.f;
    }
    if (r + 1 < r1) {
        const float* p = H + (r + 1) * FEAT;
        h0b = p[lane]; h1b = (lane < 36) ? p[64 + lane] : 0.f;
    }
    for (; r + 2 <= r1; r += 2) {
        float h0c = 0.f, h1c = 0.f, h0d = 0.f, h1d = 0.f;
        if (r + 2 < r1) {
            const float* p = H + (r + 2) * FEAT;
            h0c = p[lane]; h1c = (lane < 36) ? p[64 + lane] : 0.f;
        }
        if (r + 3 < r1) {
            const float* p = H + (r + 3) * FEAT;
            h0d = p[lane]; h1d = (lane < 36) ? p[64 + lane] : 0.f;
        }
        float pa = h0a * q0 + h1a * q1;
        float pb = h0b * q0 + h1b * q1;
#pragma unroll
        for (int o = 1; o < 64; o <<= 1) {
            pa += __shfl_xor(pa, o);
            pb += __shfl_xor(pb, o);
        }
        float ea = expf(pa), eb = expf(pb);
        dacc += ea + eb;                       // uniform across lanes
        int idx = (int)(r - r0);
        my_e = (idx == lane) ? ea : my_e;      // lane idx keeps row r's e
        my_e = (idx + 1 == lane) ? eb : my_e;  // lane idx+1 keeps row r+1's e
        c0a += ea * h0a + eb * h0b;
        c1a += ea * h1a + eb * h1b;
        h0a = h0c; h1a = h1c; h0b = h0d; h1b = h1d;
    }
    if (r < r1) {   // tail row (already in h0a/h1a)
        float pa = h0a * q0 + h1a * q1;
#pragma unroll
        for (int o = 1; o < 64; o <<= 1) pa += __shfl_xor(pa, o);
        float ea = expf(pa);
        dacc += ea;
        my_e = ((int)(r - r0) == lane) ? ea : my_e;
        c0a += ea * h0a;
        c1a += ea * h1a;
    }
    // ---- wave-wide scatter: one atomic instruction per wave ----
    int cnt = (int)(r1 - r0);                  // <= 64
    if (lane < cnt) {
        int c = cont[r0 + lane];               // coalesced
        atomicAdd(ws + WS_ADD + c, my_e);
    }
    // ---- block partials ----
    s_ct[w][lane] = c0a;
    if (lane < 36) s_ct[w][64 + lane] = c1a;
    if (lane == 0) s_d[w] = dacc;
    __syncthreads();
    if (t < FEAT)
        pt[(size_t)t * NBLK23 + blockIdx.x] =
            s_ct[0][t] + s_ct[1][t] + s_ct[2][t] + s_ct[3][t];
    if (t == FEAT)
        pt[(size_t)FEAT * NBLK23 + blockIdx.x] = s_d[0] + s_d[1] + s_d[2] + s_d[3];
}

// ------- K3r4: per-column partial reduce (coalesced); last block does k4 -----
__global__ void k3r4_reduce(const float* __restrict__ pt,
                            const float* __restrict__ l1_W, const float* __restrict__ l1_b,
                            float* __restrict__ ws) {
    __shared__ float sw[4];
    __shared__ float s_t[152];
    __shared__ float s_den;
    __shared__ int s_last;
    int col = blockIdx.x;           // 0..100 (100 = denom)
    int t = threadIdx.x;
    const float* p = pt + (size_t)col * NBLK23;
    float s = 0.f;
#pragma unroll
    for (int k = 0; k < NBLK23 / 256; ++k) s += p[t + k * 256];
#pragma unroll
    for (int o = 1; o < 64; o <<= 1) s += __shfl_xor(s, o);
    if ((t & 63) == 0) sw[t >> 6] = s;
    __syncthreads();
    if (t == 0) {
        float tot = sw[0] + sw[1] + sw[2] + sw[3];
        if (col < FEAT) ws[WS_CT + col] = tot;
        else ws[WS_DENOM] = tot;
    }
    __threadfence();
    __syncthreads();
    if (t == 0) {
        int old = atomicAdd((int*)ws + WS_CNT1, 1);
        s_last = (old == NCOL - 1) ? 1 : 0;
    }
    __syncthreads();
    if (!s_last) return;

    // ---- last block: k4  (temp = [h ; ct/denom], e_t = sigmoid(l1), scale) --
    __threadfence();
    if (t == 0) {
        float d = ws[WS_DENOM];
        s_den = d;
        ws[WS_SCALE] = ws[WS_P2] / d;
    }
    __syncthreads();
    if (t < HID) s_t[t] = ws[WS_H + t];
    if (t < FEAT) s_t[HID + t] = ws[WS_CT + t] / s_den;
    __syncthreads();
    if (t < 200) {
        float acc = l1_b[t];
        const float* wv = l1_W + t * 150;
        for (int k = 0; k < 150; ++k) acc += wv[k] * s_t[k];
        ws[WS_ET + t] = sigm(acc);
    }
}

// ------- K5: out[r] = p1*(l2_W[r].e_t + b) + scale*add[r]; online (m,s); -----
// last block merges block partials -> lse.
__global__ void __launch_bounds__(256)
k5_vocab(const float* __restrict__ l2_W, const float* __restrict__ l2_b,
         float* __restrict__ ws, float* __restrict__ outv) {
    __shared__ float4 s_e[50];
    __shared__ float s_ms[8];
    __shared__ int s_last;
    int t = threadIdx.x, w = t >> 6, lane = t & 63;
    if (t < 50) s_e[t] = ((const float4*)(ws + WS_ET))[t];
    __syncthreads();
    float p1 = ws[WS_P1], scale = ws[WS_SCALE];
    const float* add = ws + WS_ADD;
    float m = -1e30f, s = 0.f;
    for (int r = blockIdx.x * 4 + w; r < NOUT; r += NW5) {
        float acc = 0.f;
        if (r < CQ && lane < 50) {
            float4 a = ((const float4*)l2_W)[(size_t)r * 50 + lane];
            float4 b = s_e[lane];
            acc = a.x * b.x + a.y * b.y + a.z * b.z + a.w * b.w;
        }
#pragma unroll
        for (int o = 32; o > 0; o >>= 1) acc += __shfl_down(acc, o);
        if (lane == 0) {
            float val = (r < CQ) ? p1 * (acc + l2_b[r]) + scale * add[r]
                                 : scale * add[r];
            outv[r] = val;
            float mn = fmaxf(m, val);
            s = s * expf(m - mn) + expf(val - mn);
            m = mn;
        }
    }
    if (lane == 0) { s_ms[w * 2] = m; s_ms[w * 2 + 1] = s; }
    __syncthreads();
    float* msbuf = ws + WS_MS;
    if (t == 0) {
        float mg = s_ms[0], sg = s_ms[1];
        for (int k = 1; k < 4; ++k) {
            float mb = s_ms[2 * k], sb = s_ms[2 * k + 1];
            float mn = fmaxf(mg, mb);
            sg = sg * expf(mg - mn) + sb * expf(mb - mn);
            mg = mn;
        }
        msbuf[blockIdx.x * 2] = mg;
        msbuf[blockIdx.x * 2 + 1] = sg;
    }
    __threadfence();
    __syncthreads();
    if (t == 0) {
        int old = atomicAdd((int*)ws + WS_CNT2, 1);
        s_last = (old == NBLK5 - 1) ? 1 : 0;
    }
    __syncthreads();
    if (!s_last) return;

    __threadfence();
    float mg = -1e30f, sg = 0.f;
    for (int k = t; k < NBLK5; k += 256) {
        float mb = msbuf[2 * k], sb = msbuf[2 * k + 1];
        float mn = fmaxf(mg, mb);
        sg = sg * expf(mg - mn) + sb * expf(mb - mn);
        mg = mn;
    }
#pragma unroll
    for (int o = 1; o < 64; o <<= 1) {
        float mb = __shfl_xor(mg, o), sb = __shfl_xor(sg, o);
        float mn = fmaxf(mg, mb);
        sg = sg * expf(mg - mn) + sb * expf(mb - mn);
        mg = mn;
    }
    if (lane == 0) { s_ms[w * 2] = mg; s_ms[w * 2 + 1] = sg; }
    __syncthreads();
    if (t == 0) {
        float M = s_ms[0], S = s_ms[1];
        for (int k = 1; k < 4; ++k) {
            float mb = s_ms[2 * k], sb = s_ms[2 * k + 1];
            float mn = fmaxf(M, mb);
            S = S * expf(M - mn) + sb * expf(mb - mn);
            M = mn;
        }
        ws[WS_LSE] = M + logf(S);
    }
}

// ---------------- K7c: final subtract ----------------
__global__ void k7c_final(const float* __restrict__ outv, const float* __restrict__ ws,
                          float* __restrict__ dout) {
    float lse = ws[WS_LSE];
    int j = blockIdx.x * blockDim.x + threadIdx.x;
    if (j < NOUT) dout[j] = outv[j] - lse;
}

extern "C" void kernel_launch(void* const* d_in, const int* in_sizes, int n_in,
                              void* d_out, int out_size, void* d_ws, size_t ws_size,
                              hipStream_t stream) {
    const float* H    = (const float*)d_in[0];
    const float* y    = (const float*)d_in[1];
    const float* h0   = (const float*)d_in[2];
    const float* c0   = (const float*)d_in[3];
    const int*   cont = (const int*)d_in[4];
    // d_in[5] = ext scalar (1000), hardcoded
    const float* W_ih = (const float*)d_in[6];
    const float* W_hh = (const float*)d_in[7];
    const float* b_ih = (const float*)d_in[8];
    const float* b_hh = (const float*)d_in[9];
    const float* w_h_W = (const float*)d_in[10];
    const float* w_h_b = (const float*)d_in[11];
    const float* l1_W = (const float*)d_in[12];
    const float* l1_b = (const float*)d_in[13];
    const float* l2_W = (const float*)d_in[14];
    const float* l2_b = (const float*)d_in[15];
    const float* l3_W = (const float*)d_in[16];
    const float* l3_b = (const float*)d_in[17];
    const float* l4_W = (const float*)d_in[18];
    const float* l4_b = (const float*)d_in[19];

    float* ws  = (float*)d_ws;
    float* out = (float*)d_out;

    k1_lstm<<<64, 256, 0, stream>>>(y, h0, c0, W_ih, W_hh, b_ih, b_hh,
                                    w_h_W, w_h_b, l3_W, l3_b, l4_W, l4_b, ws, out);

    k23_fused<<<NBLK23, 256, 0, stream>>>(H, cont, ws, ws + WS_PT);

    k3r4_reduce<<<NCOL, 256, 0, stream>>>(ws + WS_PT, l1_W, l1_b, ws);

    k5_vocab<<<NBLK5, 256, 0, stream>>>(l2_W, l2_b, ws, ws + WS_OUT);

    k7c_final<<<(NOUT + 255) / 256, 256, 0, stream>>>(ws + WS_OUT, ws, out);
}

// Round 9
// 93.296 us; speedup vs baseline: 2.1543x; 1.3560x over previous
//
#include <hip/hip_runtime.h>
#include <math.h>

#define L 250000
#define FEAT 100
#define HID 50
#define HS 165
#define CQ 50257
#define EXTV 1000
#define NOUT (CQ + EXTV)   // 51257

#define NBLK23 1024
#define NW23 (NBLK23 * 4)   // 4096 waves, ~61 rows/wave
#define NBLK5 ((NOUT + 255) / 256)   // 201 blocks, thread-per-row
#define NCOL 101            // 100 ct cols + denom

// workspace float offsets
#define WS_Q     0      // 100
#define WS_P1    100
#define WS_P2    101
#define WS_SCALE 102    // p2/denom
#define WS_DENOM 103
#define WS_CT    104    // 100
#define WS_ET    204    // 200 (16B aligned)
#define WS_H     404    // 50
#define WS_LSE   454
#define WS_CNT1  456    // int counter (k3r4 lastblock)
#define WS_CNT2  457    // int counter (k5 lastblock)
#define WS_ADD   512    // 51257 raw scatter accumulator
#define WS_OUT   51776  // 51257 pre-logsoftmax vocab
#define WS_MS    103040 // NBLK5*2 (m,s) pairs
#define WS_PT    104448 // 101*1024 block partials [col][blk]

__device__ __forceinline__ float sigm(float x) { return 1.f / (1.f + expf(-x)); }

// ---------------- K1: LSTM step + q + p1/p2 ; zero add_buf + counters --------
__global__ void k1_lstm(const float* __restrict__ y, const float* __restrict__ h0,
                        const float* __restrict__ c0,
                        const float* __restrict__ W_ih, const float* __restrict__ W_hh,
                        const float* __restrict__ b_ih, const float* __restrict__ b_hh,
                        const float* __restrict__ w_h_W, const float* __restrict__ w_h_b,
                        const float* __restrict__ l3_W, const float* __restrict__ l3_b,
                        const float* __restrict__ l4_W, const float* __restrict__ l4_b,
                        float* __restrict__ ws, float* __restrict__ out) {
    int t = threadIdx.x;
    if (blockIdx.x != 0) {
        float* add = ws + WS_ADD;
        for (int i = (blockIdx.x - 1) * 256 + t; i < NOUT; i += 63 * 256) add[i] = 0.f;
        return;
    }
    __shared__ float s_y[HS], s_h[HID], s_c[HID], s_g[4 * HID], s_hn[HID];
    if (t < HS) s_y[t] = y[t];
    if (t < HID) { s_h[t] = h0[t]; s_c[t] = c0[t]; }
    if (t == 203) ((int*)ws)[WS_CNT1] = 0;
    if (t == 204) ((int*)ws)[WS_CNT2] = 0;
    __syncthreads();
    if (t < 4 * HID) {
        float acc = b_ih[t] + b_hh[t];
        const float* wi = W_ih + t * HS;
        for (int k = 0; k < HS; ++k) acc += wi[k] * s_y[k];
        const float* wh = W_hh + t * HID;
        for (int k = 0; k < HID; ++k) acc += wh[k] * s_h[k];
        s_g[t] = acc;
    }
    __syncthreads();
    if (t < HID) {
        float ig = sigm(s_g[t]);
        float fg = sigm(s_g[HID + t]);
        float gg = tanhf(s_g[2 * HID + t]);
        float og = sigm(s_g[3 * HID + t]);
        float cn = fg * s_c[t] + ig * gg;
        float hn = og * tanhf(cn);
        s_hn[t] = hn;
        ws[WS_H + t] = hn;
        out[NOUT + t] = hn;          // h_new output
        out[NOUT + HID + t] = cn;    // c_new output
    }
    __syncthreads();
    if (t < FEAT) {
        float acc = w_h_b[t];
        const float* w = w_h_W + t * HID;
        for (int k = 0; k < HID; ++k) acc += w[k] * s_hn[k];
        ws[WS_Q + t] = acc;
    }
    if (t == 200) {
        float acc = l3_b[0];
        for (int k = 0; k < HID; ++k) acc += l3_W[k] * s_hn[k];
        ws[WS_P1] = sigm(acc);
    }
    if (t == 201) {
        float acc = l4_b[0];
        for (int k = 0; k < HID; ++k) acc += l4_W[k] * s_hn[k];
        ws[WS_P2] = sigm(acc);
    }
}

// ------- K23: wave-per-row pass over H: partials + wave-wide scatter ---------
__global__ void __launch_bounds__(256)
k23_fused(const float* __restrict__ H, const int* __restrict__ cont,
          float* __restrict__ ws, float* __restrict__ pt) {
    __shared__ float s_ct[4][FEAT];
    __shared__ float s_d[4];
    int t = threadIdx.x;
    int w = t >> 6, lane = t & 63;
    long wid = (long)blockIdx.x * 4 + w;
    float q0 = ws[WS_Q + lane];
    float q1 = (lane < 36) ? ws[WS_Q + 64 + lane] : 0.f;
    long r0 = (wid * L) / NW23;
    long r1 = ((wid + 1) * L) / NW23;
    float c0a = 0.f, c1a = 0.f, dacc = 0.f;
    float my_e = 0.f;

    long r = r0;
    float h0a = 0.f, h1a = 0.f, h0b = 0.f, h1b = 0.f;
    if (r < r1) {
        const float* p = H + r * FEAT;
        h0a = p[lane]; h1a = (lane < 36) ? p[64 + lane] : 0.f;
    }
    if (r + 1 < r1) {
        const float* p = H + (r + 1) * FEAT;
        h0b = p[lane]; h1b = (lane < 36) ? p[64 + lane] : 0.f;
    }
    for (; r + 2 <= r1; r += 2) {
        float h0c = 0.f, h1c = 0.f, h0d = 0.f, h1d = 0.f;
        if (r + 2 < r1) {
            const float* p = H + (r + 2) * FEAT;
            h0c = p[lane]; h1c = (lane < 36) ? p[64 + lane] : 0.f;
        }
        if (r + 3 < r1) {
            const float* p = H + (r + 3) * FEAT;
            h0d = p[lane]; h1d = (lane < 36) ? p[64 + lane] : 0.f;
        }
        float pa = h0a * q0 + h1a * q1;
        float pb = h0b * q0 + h1b * q1;
#pragma unroll
        for (int o = 1; o < 64; o <<= 1) {
            pa += __shfl_xor(pa, o);
            pb += __shfl_xor(pb, o);
        }
        float ea = expf(pa), eb = expf(pb);
        dacc += ea + eb;                       // uniform across lanes
        int idx = (int)(r - r0);
        my_e = (idx == lane) ? ea : my_e;      // lane idx keeps row r's e
        my_e = (idx + 1 == lane) ? eb : my_e;  // lane idx+1 keeps row r+1's e
        c0a += ea * h0a + eb * h0b;
        c1a += ea * h1a + eb * h1b;
        h0a = h0c; h1a = h1c; h0b = h0d; h1b = h1d;
    }
    if (r < r1) {   // tail row (already in h0a/h1a)
        float pa = h0a * q0 + h1a * q1;
#pragma unroll
        for (int o = 1; o < 64; o <<= 1) pa += __shfl_xor(pa, o);
        float ea = expf(pa);
        dacc += ea;
        my_e = ((int)(r - r0) == lane) ? ea : my_e;
        c0a += ea * h0a;
        c1a += ea * h1a;
    }
    // ---- wave-wide scatter: one atomic instruction per wave ----
    int cnt = (int)(r1 - r0);                  // <= 64
    if (lane < cnt) {
        int c = cont[r0 + lane];               // coalesced
        atomicAdd(ws + WS_ADD + c, my_e);
    }
    // ---- block partials ----
    s_ct[w][lane] = c0a;
    if (lane < 36) s_ct[w][64 + lane] = c1a;
    if (lane == 0) s_d[w] = dacc;
    __syncthreads();
    if (t < FEAT)
        pt[(size_t)t * NBLK23 + blockIdx.x] =
            s_ct[0][t] + s_ct[1][t] + s_ct[2][t] + s_ct[3][t];
    if (t == FEAT)
        pt[(size_t)FEAT * NBLK23 + blockIdx.x] = s_d[0] + s_d[1] + s_d[2] + s_d[3];
}

// ------- K3r4: per-column partial reduce (coalesced); last block does k4 -----
__global__ void k3r4_reduce(const float* __restrict__ pt,
                            const float* __restrict__ l1_W, const float* __restrict__ l1_b,
                            float* __restrict__ ws) {
    __shared__ float sw[4];
    __shared__ float s_t[152];
    __shared__ float s_den;
    __shared__ int s_last;
    int col = blockIdx.x;           // 0..100 (100 = denom)
    int t = threadIdx.x;
    const float* p = pt + (size_t)col * NBLK23;
    float s = 0.f;
#pragma unroll
    for (int k = 0; k < NBLK23 / 256; ++k) s += p[t + k * 256];
#pragma unroll
    for (int o = 1; o < 64; o <<= 1) s += __shfl_xor(s, o);
    if ((t & 63) == 0) sw[t >> 6] = s;
    __syncthreads();
    if (t == 0) {
        float tot = sw[0] + sw[1] + sw[2] + sw[3];
        if (col < FEAT) ws[WS_CT + col] = tot;
        else ws[WS_DENOM] = tot;
    }
    __threadfence();
    __syncthreads();
    if (t == 0) {
        int old = atomicAdd((int*)ws + WS_CNT1, 1);
        s_last = (old == NCOL - 1) ? 1 : 0;
    }
    __syncthreads();
    if (!s_last) return;

    // ---- last block: k4  (temp = [h ; ct/denom], e_t = sigmoid(l1), scale) --
    __threadfence();
    if (t == 0) {
        float d = ws[WS_DENOM];
        s_den = d;
        ws[WS_SCALE] = ws[WS_P2] / d;
    }
    __syncthreads();
    if (t < HID) s_t[t] = ws[WS_H + t];
    if (t < FEAT) s_t[HID + t] = ws[WS_CT + t] / s_den;
    __syncthreads();
    if (t < 200) {
        float acc = l1_b[t];
        const float* wv = l1_W + t * 150;
        for (int k = 0; k < 150; ++k) acc += wv[k] * s_t[k];
        ws[WS_ET + t] = sigm(acc);
    }
}

// ------- K5: thread-per-row GEMV: out[r] = p1*(l2_W[r].e_t+b) + scale*add[r];
// per-thread (m,s), block merge, last block -> lse.
__global__ void __launch_bounds__(256)
k5_vocab(const float* __restrict__ l2_W, const float* __restrict__ l2_b,
         float* __restrict__ ws, float* __restrict__ outv) {
    __shared__ float4 s_e[50];
    __shared__ float s_ms[8];
    __shared__ int s_last;
    int t = threadIdx.x, w = t >> 6, lane = t & 63;
    if (t < 50) s_e[t] = ((const float4*)(ws + WS_ET))[t];
    __syncthreads();
    float p1 = ws[WS_P1], scale = ws[WS_SCALE];
    const float* add = ws + WS_ADD;
    int r = blockIdx.x * 256 + t;
    float m = -1e30f, s = 0.f;
    if (r < NOUT) {
        float val;
        if (r < CQ) {
            const float4* wrow = (const float4*)l2_W + (size_t)r * 50;
            float acc = 0.f;
#pragma unroll 10
            for (int k = 0; k < 50; ++k) {
                float4 a = wrow[k], b = s_e[k];
                acc += a.x * b.x + a.y * b.y + a.z * b.z + a.w * b.w;
            }
            val = p1 * (acc + l2_b[r]) + scale * add[r];
        } else {
            val = scale * add[r];
        }
        outv[r] = val;
        m = val; s = 1.f;
    }
    // wave (m,s) butterfly
#pragma unroll
    for (int o = 1; o < 64; o <<= 1) {
        float mb = __shfl_xor(m, o), sb = __shfl_xor(s, o);
        float mn = fmaxf(m, mb);
        s = s * expf(m - mn) + sb * expf(mb - mn);
        m = mn;
    }
    if (lane == 0) { s_ms[w * 2] = m; s_ms[w * 2 + 1] = s; }
    __syncthreads();
    float* msbuf = ws + WS_MS;
    if (t == 0) {
        float mg = s_ms[0], sg = s_ms[1];
        for (int k = 1; k < 4; ++k) {
            float mb = s_ms[2 * k], sb = s_ms[2 * k + 1];
            float mn = fmaxf(mg, mb);
            sg = sg * expf(mg - mn) + sb * expf(mb - mn);
            mg = mn;
        }
        msbuf[blockIdx.x * 2] = mg;
        msbuf[blockIdx.x * 2 + 1] = sg;
    }
    __threadfence();
    __syncthreads();
    if (t == 0) {
        int old = atomicAdd((int*)ws + WS_CNT2, 1);
        s_last = (old == NBLK5 - 1) ? 1 : 0;
    }
    __syncthreads();
    if (!s_last) return;

    __threadfence();
    float mg = -1e30f, sg = 0.f;
    for (int k = t; k < NBLK5; k += 256) {
        float mb = msbuf[2 * k], sb = msbuf[2 * k + 1];
        float mn = fmaxf(mg, mb);
        sg = sg * expf(mg - mn) + sb * expf(mb - mn);
        mg = mn;
    }
#pragma unroll
    for (int o = 1; o < 64; o <<= 1) {
        float mb = __shfl_xor(mg, o), sb = __shfl_xor(sg, o);
        float mn = fmaxf(mg, mb);
        sg = sg * expf(mg - mn) + sb * expf(mb - mn);
        mg = mn;
    }
    if (lane == 0) { s_ms[w * 2] = mg; s_ms[w * 2 + 1] = sg; }
    __syncthreads();
    if (t == 0) {
        float M = s_ms[0], S = s_ms[1];
        for (int k = 1; k < 4; ++k) {
            float mb = s_ms[2 * k], sb = s_ms[2 * k + 1];
            float mn = fmaxf(M, mb);
            S = S * expf(M - mn) + sb * expf(mb - mn);
            M = mn;
        }
        ws[WS_LSE] = M + logf(S);
    }
}

// ---------------- K7c: final subtract ----------------
__global__ void k7c_final(const float* __restrict__ outv, const float* __restrict__ ws,
                          float* __restrict__ dout) {
    float lse = ws[WS_LSE];
    int j = blockIdx.x * blockDim.x + threadIdx.x;
    if (j < NOUT) dout[j] = outv[j] - lse;
}

extern "C" void kernel_launch(void* const* d_in, const int* in_sizes, int n_in,
                              void* d_out, int out_size, void* d_ws, size_t ws_size,
                              hipStream_t stream) {
    const float* H    = (const float*)d_in[0];
    const float* y    = (const float*)d_in[1];
    const float* h0   = (const float*)d_in[2];
    const float* c0   = (const float*)d_in[3];
    const int*   cont = (const int*)d_in[4];
    // d_in[5] = ext scalar (1000), hardcoded
    const float* W_ih = (const float*)d_in[6];
    const float* W_hh = (const float*)d_in[7];
    const float* b_ih = (const float*)d_in[8];
    const float* b_hh = (const float*)d_in[9];
    const float* w_h_W = (const float*)d_in[10];
    const float* w_h_b = (const float*)d_in[11];
    const float* l1_W = (const float*)d_in[12];
    const float* l1_b = (const float*)d_in[13];
    const float* l2_W = (const float*)d_in[14];
    const float* l2_b = (const float*)d_in[15];
    const float* l3_W = (const float*)d_in[16];
    const float* l3_b = (const float*)d_in[17];
    const float* l4_W = (const float*)d_in[18];
    const float* l4_b = (const float*)d_in[19];

    float* ws  = (float*)d_ws;
    float* out = (float*)d_out;

    k1_lstm<<<64, 256, 0, stream>>>(y, h0, c0, W_ih, W_hh, b_ih, b_hh,
                                    w_h_W, w_h_b, l3_W, l3_b, l4_W, l4_b, ws, out);

    k23_fused<<<NBLK23, 256, 0, stream>>>(H, cont, ws, ws + WS_PT);

    k3r4_reduce<<<NCOL, 256, 0, stream>>>(ws + WS_PT, l1_W, l1_b, ws);

    k5_vocab<<<NBLK5, 256, 0, stream>>>(l2_W, l2_b, ws, ws + WS_OUT);

    k7c_final<<<(NOUT + 255) / 256, 256, 0, stream>>>(ws + WS_OUT, ws, out);
}

// Round 10
// 82.085 us; speedup vs baseline: 2.4486x; 1.1366x over previous
//
#include <hip/hip_runtime.h>
#include <math.h>

#define L 250000
#define FEAT 100
#define HID 50
#define HS 165
#define CQ 50257
#define EXTV 1000
#define NOUT (CQ + EXTV)   // 51257

#define NBLK23 2048
#define NW23 (NBLK23 * 4)   // 8192 waves, ~30-31 rows/wave
#define NBLK5 ((NOUT + 255) / 256)   // 201 blocks, thread-per-row
#define NCOL 101            // 100 ct cols + denom

// workspace float offsets
#define WS_Q     0      // 100
#define WS_P1    100
#define WS_P2    101
#define WS_SCALE 102    // p2/denom
#define WS_DENOM 103
#define WS_CT    104    // 100
#define WS_ET    204    // 200 (16B aligned)
#define WS_H     404    // 50
#define WS_LSE   454
#define WS_CNT1  456    // int counter (k3r4 lastblock)
#define WS_CNT2  457    // int counter (k5 lastblock)
#define WS_ADD   512    // 51257 raw scatter accumulator
#define WS_OUT   51776  // 51257 pre-logsoftmax vocab
#define WS_MS    103040 // NBLK5*2 (m,s) pairs
#define WS_PT    104448 // 101*2048 block partials [col][blk]

__device__ __forceinline__ float sigm(float x) { return 1.f / (1.f + expf(-x)); }

// ---------------- K1: LSTM step + q + p1/p2 ; zero add_buf + counters --------
__global__ void k1_lstm(const float* __restrict__ y, const float* __restrict__ h0,
                        const float* __restrict__ c0,
                        const float* __restrict__ W_ih, const float* __restrict__ W_hh,
                        const float* __restrict__ b_ih, const float* __restrict__ b_hh,
                        const float* __restrict__ w_h_W, const float* __restrict__ w_h_b,
                        const float* __restrict__ l3_W, const float* __restrict__ l3_b,
                        const float* __restrict__ l4_W, const float* __restrict__ l4_b,
                        float* __restrict__ ws, float* __restrict__ out) {
    int t = threadIdx.x;
    if (blockIdx.x != 0) {
        float* add = ws + WS_ADD;
        for (int i = (blockIdx.x - 1) * 256 + t; i < NOUT; i += 63 * 256) add[i] = 0.f;
        return;
    }
    __shared__ float s_y[HS], s_h[HID], s_c[HID], s_g[4 * HID], s_hn[HID];
    if (t < HS) s_y[t] = y[t];
    if (t < HID) { s_h[t] = h0[t]; s_c[t] = c0[t]; }
    if (t == 203) ((int*)ws)[WS_CNT1] = 0;
    if (t == 204) ((int*)ws)[WS_CNT2] = 0;
    __syncthreads();
    if (t < 4 * HID) {
        float acc = b_ih[t] + b_hh[t];
        const float* wi = W_ih + t * HS;
        for (int k = 0; k < HS; ++k) acc += wi[k] * s_y[k];
        const float* wh = W_hh + t * HID;
        for (int k = 0; k < HID; ++k) acc += wh[k] * s_h[k];
        s_g[t] = acc;
    }
    __syncthreads();
    if (t < HID) {
        float ig = sigm(s_g[t]);
        float fg = sigm(s_g[HID + t]);
        float gg = tanhf(s_g[2 * HID + t]);
        float og = sigm(s_g[3 * HID + t]);
        float cn = fg * s_c[t] + ig * gg;
        float hn = og * tanhf(cn);
        s_hn[t] = hn;
        ws[WS_H + t] = hn;
        out[NOUT + t] = hn;          // h_new output
        out[NOUT + HID + t] = cn;    // c_new output
    }
    __syncthreads();
    if (t < FEAT) {
        float acc = w_h_b[t];
        const float* w = w_h_W + t * HID;
        for (int k = 0; k < HID; ++k) acc += w[k] * s_hn[k];
        ws[WS_Q + t] = acc;
    }
    if (t == 200) {
        float acc = l3_b[0];
        for (int k = 0; k < HID; ++k) acc += l3_W[k] * s_hn[k];
        ws[WS_P1] = sigm(acc);
    }
    if (t == 201) {
        float acc = l4_b[0];
        for (int k = 0; k < HID; ++k) acc += l4_W[k] * s_hn[k];
        ws[WS_P2] = sigm(acc);
    }
}

// ------- K23: wave-per-row pass over H, 4 rows/iter (4 independent butterfly
// chains), 8 blocks/CU. Partials to pt, wave-wide scatter at end. ------------
__global__ void __launch_bounds__(256, 8)
k23_fused(const float* __restrict__ H, const int* __restrict__ cont,
          float* __restrict__ ws, float* __restrict__ pt) {
    __shared__ float s_ct[4][FEAT];
    __shared__ float s_d[4];
    int t = threadIdx.x;
    int w = t >> 6, lane = t & 63;
    long wid = (long)blockIdx.x * 4 + w;
    float q0 = ws[WS_Q + lane];
    float q1 = (lane < 36) ? ws[WS_Q + 64 + lane] : 0.f;
    long r0 = (wid * L) / NW23;
    long r1 = ((wid + 1) * L) / NW23;
    float c0a = 0.f, c1a = 0.f, dacc = 0.f, my_e = 0.f;

    float h0[4], h1[4];
#pragma unroll
    for (int j = 0; j < 4; ++j) { h0[j] = 0.f; h1[j] = 0.f; }
#pragma unroll
    for (int j = 0; j < 4; ++j) {
        if (r0 + j < r1) {
            const float* p = H + (r0 + j) * FEAT;
            h0[j] = p[lane]; h1[j] = (lane < 36) ? p[64 + lane] : 0.f;
        }
    }
    long r = r0;
    for (; r + 4 <= r1; r += 4) {
        float n0[4], n1[4];
#pragma unroll
        for (int j = 0; j < 4; ++j) { n0[j] = 0.f; n1[j] = 0.f; }
#pragma unroll
        for (int j = 0; j < 4; ++j) {
            if (r + 4 + j < r1) {
                const float* p = H + (r + 4 + j) * FEAT;
                n0[j] = p[lane]; n1[j] = (lane < 36) ? p[64 + lane] : 0.f;
            }
        }
        float pd[4];
#pragma unroll
        for (int j = 0; j < 4; ++j) pd[j] = h0[j] * q0 + h1[j] * q1;
#pragma unroll
        for (int o = 1; o < 64; o <<= 1) {
#pragma unroll
            for (int j = 0; j < 4; ++j) pd[j] += __shfl_xor(pd[j], o);
        }
        float e0 = expf(pd[0]), e1 = expf(pd[1]), e2 = expf(pd[2]), e3 = expf(pd[3]);
        dacc += e0 + e1 + e2 + e3;                 // uniform across lanes
        int idx = (int)(r - r0);
        my_e = (idx     == lane) ? e0 : my_e;
        my_e = (idx + 1 == lane) ? e1 : my_e;
        my_e = (idx + 2 == lane) ? e2 : my_e;
        my_e = (idx + 3 == lane) ? e3 : my_e;
        c0a += e0 * h0[0] + e1 * h0[1] + e2 * h0[2] + e3 * h0[3];
        c1a += e0 * h1[0] + e1 * h1[1] + e2 * h1[2] + e3 * h1[3];
#pragma unroll
        for (int j = 0; j < 4; ++j) { h0[j] = n0[j]; h1[j] = n1[j]; }
    }
    // tail: up to 3 rows, already resident in h0/h1 (zeros beyond r1)
    int rem = (int)(r1 - r);
    if (rem > 0) {
        float pd[3];
#pragma unroll
        for (int j = 0; j < 3; ++j) pd[j] = h0[j] * q0 + h1[j] * q1;
#pragma unroll
        for (int o = 1; o < 64; o <<= 1) {
#pragma unroll
            for (int j = 0; j < 3; ++j) pd[j] += __shfl_xor(pd[j], o);
        }
#pragma unroll
        for (int j = 0; j < 3; ++j) {
            if (j < rem) {
                float e = expf(pd[j]);
                dacc += e;
                my_e = ((int)(r - r0) + j == lane) ? e : my_e;
                c0a += e * h0[j];
                c1a += e * h1[j];
            }
        }
    }
    // ---- wave-wide scatter: one atomic instruction per wave ----
    int cnt = (int)(r1 - r0);                  // ~30-31 <= 64
    if (lane < cnt) {
        int c = cont[r0 + lane];               // coalesced
        atomicAdd(ws + WS_ADD + c, my_e);
    }
    // ---- block partials ----
    s_ct[w][lane] = c0a;
    if (lane < 36) s_ct[w][64 + lane] = c1a;
    if (lane == 0) s_d[w] = dacc;
    __syncthreads();
    if (t < FEAT)
        pt[(size_t)t * NBLK23 + blockIdx.x] =
            s_ct[0][t] + s_ct[1][t] + s_ct[2][t] + s_ct[3][t];
    if (t == FEAT)
        pt[(size_t)FEAT * NBLK23 + blockIdx.x] = s_d[0] + s_d[1] + s_d[2] + s_d[3];
}

// ------- K3r4: per-column partial reduce (coalesced); last block does k4 -----
__global__ void k3r4_reduce(const float* __restrict__ pt,
                            const float* __restrict__ l1_W, const float* __restrict__ l1_b,
                            float* __restrict__ ws) {
    __shared__ float sw[4];
    __shared__ float s_t[152];
    __shared__ float s_den;
    __shared__ int s_last;
    int col = blockIdx.x;           // 0..100 (100 = denom)
    int t = threadIdx.x;
    const float* p = pt + (size_t)col * NBLK23;
    float s = 0.f;
#pragma unroll
    for (int k = 0; k < NBLK23 / 256; ++k) s += p[t + k * 256];
#pragma unroll
    for (int o = 1; o < 64; o <<= 1) s += __shfl_xor(s, o);
    if ((t & 63) == 0) sw[t >> 6] = s;
    __syncthreads();
    if (t == 0) {
        float tot = sw[0] + sw[1] + sw[2] + sw[3];
        if (col < FEAT) ws[WS_CT + col] = tot;
        else ws[WS_DENOM] = tot;
    }
    __threadfence();
    __syncthreads();
    if (t == 0) {
        int old = atomicAdd((int*)ws + WS_CNT1, 1);
        s_last = (old == NCOL - 1) ? 1 : 0;
    }
    __syncthreads();
    if (!s_last) return;

    // ---- last block: k4  (temp = [h ; ct/denom], e_t = sigmoid(l1), scale) --
    __threadfence();
    if (t == 0) {
        float d = ws[WS_DENOM];
        s_den = d;
        ws[WS_SCALE] = ws[WS_P2] / d;
    }
    __syncthreads();
    if (t < HID) s_t[t] = ws[WS_H + t];
    if (t < FEAT) s_t[HID + t] = ws[WS_CT + t] / s_den;
    __syncthreads();
    if (t < 200) {
        float acc = l1_b[t];
        const float* wv = l1_W + t * 150;
        for (int k = 0; k < 150; ++k) acc += wv[k] * s_t[k];
        ws[WS_ET + t] = sigm(acc);
    }
}

// ------- K5: thread-per-row GEMV: out[r] = p1*(l2_W[r].e_t+b) + scale*add[r];
// per-thread (m,s), block merge, last block -> lse.
__global__ void __launch_bounds__(256)
k5_vocab(const float* __restrict__ l2_W, const float* __restrict__ l2_b,
         float* __restrict__ ws, float* __restrict__ outv) {
    __shared__ float4 s_e[50];
    __shared__ float s_ms[8];
    __shared__ int s_last;
    int t = threadIdx.x, w = t >> 6, lane = t & 63;
    if (t < 50) s_e[t] = ((const float4*)(ws + WS_ET))[t];
    __syncthreads();
    float p1 = ws[WS_P1], scale = ws[WS_SCALE];
    const float* add = ws + WS_ADD;
    int r = blockIdx.x * 256 + t;
    float m = -1e30f, s = 0.f;
    if (r < NOUT) {
        float val;
        if (r < CQ) {
            const float4* wrow = (const float4*)l2_W + (size_t)r * 50;
            float acc = 0.f;
#pragma unroll 10
            for (int k = 0; k < 50; ++k) {
                float4 a = wrow[k], b = s_e[k];
                acc += a.x * b.x + a.y * b.y + a.z * b.z + a.w * b.w;
            }
            val = p1 * (acc + l2_b[r]) + scale * add[r];
        } else {
            val = scale * add[r];
        }
        outv[r] = val;
        m = val; s = 1.f;
    }
    // wave (m,s) butterfly
#pragma unroll
    for (int o = 1; o < 64; o <<= 1) {
        float mb = __shfl_xor(m, o), sb = __shfl_xor(s, o);
        float mn = fmaxf(m, mb);
        s = s * expf(m - mn) + sb * expf(mb - mn);
        m = mn;
    }
    if (lane == 0) { s_ms[w * 2] = m; s_ms[w * 2 + 1] = s; }
    __syncthreads();
    float* msbuf = ws + WS_MS;
    if (t == 0) {
        float mg = s_ms[0], sg = s_ms[1];
        for (int k = 1; k < 4; ++k) {
            float mb = s_ms[2 * k], sb = s_ms[2 * k + 1];
            float mn = fmaxf(mg, mb);
            sg = sg * expf(mg - mn) + sb * expf(mb - mn);
            mg = mn;
        }
        msbuf[blockIdx.x * 2] = mg;
        msbuf[blockIdx.x * 2 + 1] = sg;
    }
    __threadfence();
    __syncthreads();
    if (t == 0) {
        int old = atomicAdd((int*)ws + WS_CNT2, 1);
        s_last = (old == NBLK5 - 1) ? 1 : 0;
    }
    __syncthreads();
    if (!s_last) return;

    __threadfence();
    float mg = -1e30f, sg = 0.f;
    for (int k = t; k < NBLK5; k += 256) {
        float mb = msbuf[2 * k], sb = msbuf[2 * k + 1];
        float mn = fmaxf(mg, mb);
        sg = sg * expf(mg - mn) + sb * expf(mb - mn);
        mg = mn;
    }
#pragma unroll
    for (int o = 1; o < 64; o <<= 1) {
        float mb = __shfl_xor(mg, o), sb = __shfl_xor(sg, o);
        float mn = fmaxf(mg, mb);
        sg = sg * expf(mg - mn) + sb * expf(mb - mn);
        mg = mn;
    }
    if (lane == 0) { s_ms[w * 2] = mg; s_ms[w * 2 + 1] = sg; }
    __syncthreads();
    if (t == 0) {
        float M = s_ms[0], S = s_ms[1];
        for (int k = 1; k < 4; ++k) {
            float mb = s_ms[2 * k], sb = s_ms[2 * k + 1];
            float mn = fmaxf(M, mb);
            S = S * expf(M - mn) + sb * expf(mb - mn);
            M = mn;
        }
        ws[WS_LSE] = M + logf(S);
    }
}

// ---------------- K7c: final subtract ----------------
__global__ void k7c_final(const float* __restrict__ outv, const float* __restrict__ ws,
                          float* __restrict__ dout) {
    float lse = ws[WS_LSE];
    int j = blockIdx.x * blockDim.x + threadIdx.x;
    if (j < NOUT) dout[j] = outv[j] - lse;
}

extern "C" void kernel_launch(void* const* d_in, const int* in_sizes, int n_in,
                              void* d_out, int out_size, void* d_ws, size_t ws_size,
                              hipStream_t stream) {
    const float* H    = (const float*)d_in[0];
    const float* y    = (const float*)d_in[1];
    const float* h0   = (const float*)d_in[2];
    const float* c0   = (const float*)d_in[3];
    const int*   cont = (const int*)d_in[4];
    // d_in[5] = ext scalar (1000), hardcoded
    const float* W_ih = (const float*)d_in[6];
    const float* W_hh = (const float*)d_in[7];
    const float* b_ih = (const float*)d_in[8];
    const float* b_hh = (const float*)d_in[9];
    const float* w_h_W = (const float*)d_in[10];
    const float* w_h_b = (const float*)d_in[11];
    const float* l1_W = (const float*)d_in[12];
    const float* l1_b = (const float*)d_in[13];
    const float* l2_W = (const float*)d_in[14];
    const float* l2_b = (const float*)d_in[15];
    const float* l3_W = (const float*)d_in[16];
    const float* l3_b = (const float*)d_in[17];
    const float* l4_W = (const float*)d_in[18];
    const float* l4_b = (const float*)d_in[19];

    float* ws  = (float*)d_ws;
    float* out = (float*)d_out;

    k1_lstm<<<64, 256, 0, stream>>>(y, h0, c0, W_ih, W_hh, b_ih, b_hh,
                                    w_h_W, w_h_b, l3_W, l3_b, l4_W, l4_b, ws, out);

    k23_fused<<<NBLK23, 256, 0, stream>>>(H, cont, ws, ws + WS_PT);

    k3r4_reduce<<<NCOL, 256, 0, stream>>>(ws + WS_PT, l1_W, l1_b, ws);

    k5_vocab<<<NBLK5, 256, 0, stream>>>(l2_W, l2_b, ws, ws + WS_OUT);

    k7c_final<<<(NOUT + 255) / 256, 256, 0, stream>>>(ws + WS_OUT, ws, out);
}